// Round 2
// baseline (331.019 us; speedup 1.0000x reference)
//
#include <hip/hip_runtime.h>

#define SEQ    512
#define BATCH  1024
#define NTAG   54
#define TSTART 52
#define TSTOP  53
#define NW     4   // waves (batch elements) per block

// ---------------------------------------------------------------------------
// Linear-space CRF forward: u[j] = exp(alpha[j] - esum*ln2), per-wave batch elem.
// Step: u' = (sum_i Elin[j,i]*u[i]) * (exp(feat[j]) * 2^-e_lag)
//   Elin[j,i] = exp(trans[j,i])  (constant, 56 VGPRs; START row -> exactly 0)
//   e_lag     = exponent of readlane(u,0) from the PREVIOUS step (off-chain)
//   exp(feat) computed at prefetch time (4 steps early, off-chain)
// Critical chain per step: ds_write -> 14x ds_read_b128 -> 54 FMA -> 1 mul.
// ---------------------------------------------------------------------------

#define STEP(S, EF, TG, MK, EMV) do {                                         \
    alds[wv][lane] = u;                                                       \
    asm volatile("" ::: "memory");                                            \
    float efs_ = (EF) * __uint_as_float((unsigned)(127 - e_lag) << 23);       \
    float ac0 = 0.f, ac1 = 0.f, ac2 = 0.f, ac3 = 0.f;                         \
    const float4* ap_ = (const float4*)(&alds[wv][0]);                        \
    _Pragma("unroll")                                                         \
    for (int g_ = 0; g_ < 14; ++g_) {                                         \
        float4 av_ = ap_[g_];                                                 \
        ac0 = fmaf(Elin[4*g_+0], av_.x, ac0);                                 \
        ac1 = fmaf(Elin[4*g_+1], av_.y, ac1);                                 \
        ac2 = fmaf(Elin[4*g_+2], av_.z, ac2);                                 \
        ac3 = fmaf(Elin[4*g_+3], av_.w, ac3);                                 \
    }                                                                         \
    float trv_ = tlds[(TG) * NTAG + prev];  /* after critical reads */        \
    float w_  = (ac0 + ac1) + (ac2 + ac3);                                    \
    float un_ = w_ * efs_;                                                    \
    bool  up_ = (MK) > 0;                                                     \
    u = up_ ? un_ : u;                                                        \
    esum += up_ ? e_lag : 0;                                                  \
    unsigned ub_ = (unsigned)__builtin_amdgcn_readlane((int)__float_as_uint(u), 0); \
    int en_ = (int)((ub_ >> 23) & 255u) - 127;                                \
    e_lag = en_ < -40 ? -40 : (en_ > 40 ? 40 : en_);                          \
    float mf_ = ((S) == 0) ? 1.0f : (float)(MK);                              \
    gold  = fmaf(trv_ + (EMV), mf_, gold);                                    \
    msumv += (MK);                                                            \
    prev = (TG);                                                              \
} while (0)

__global__ __launch_bounds__(64 * NW) void crf_fwd_kernel(
    const float* __restrict__ em, const float* __restrict__ tr,
    const int* __restrict__ tags, const int* __restrict__ mask,
    float* __restrict__ part, int* __restrict__ msum)
{
    __shared__ float tlds[NTAG * NTAG];
    __shared__ __align__(16) float alds[NW][64];

    const int tid = threadIdx.x;
    for (int k = tid; k < NTAG * NTAG; k += 64 * NW) tlds[k] = tr[k];
    __syncthreads();

    const int wv   = tid >> 6;
    const int lane = tid & 63;
    const int b    = blockIdx.x * NW + wv;

    // --- Elin = exp(trans) rows, fully register-resident ---
    float Elin[56];
    #pragma unroll
    for (int i = 0; i < 56; ++i)
        Elin[i] = (lane < NTAG && i < NTAG) ? __expf(tlds[lane * NTAG + i]) : 0.f;
    float estop = (lane < NTAG) ? __expf(tlds[TSTOP * NTAG + lane]) : 0.f;

    // --- state ---
    float u     = (lane == TSTART) ? 1.f : 0.f;
    float gold  = 0.f;
    int   esum  = 0;
    int   e_lag = 0;
    int   prev  = TSTART;
    int   msumv = 0;

    const size_t bT = (size_t)b * NTAG;
    #define LDF(S)    ((lane < NTAG) ? em[(size_t)(S) * (BATCH * NTAG) + bT + lane] : 0.f)
    #define LDT(S)    (tags[(S) * BATCH + b])
    #define LDM(S)    (mask[(S) * BATCH + b])
    #define LDE(S,T_) (em[(size_t)(S) * (BATCH * NTAG) + bT + (T_)])

    // 4-deep prefetch (tags first -> emission gather chains off the tag)
    int   t0 = LDT(0), t1 = LDT(1), t2 = LDT(2), t3 = LDT(3);
    int   k0 = LDM(0), k1 = LDM(1), k2 = LDM(2), k3 = LDM(3);
    float F0 = __expf(LDF(0)), F1 = __expf(LDF(1)), F2 = __expf(LDF(2)), F3 = __expf(LDF(3));
    float G0 = LDE(0, t0), G1 = LDE(1, t1), G2 = LDE(2, t2), G3 = LDE(3, t3);

    for (int sb = 0; sb < SEQ; sb += 4) {
        STEP(sb + 0, F0, t0, k0, G0);
        { int sn = (sb + 4 < SEQ) ? sb + 4 : SEQ - 1;
          int tn = LDT(sn); F0 = __expf(LDF(sn)); G0 = LDE(sn, tn); t0 = tn; k0 = LDM(sn); }
        STEP(sb + 1, F1, t1, k1, G1);
        { int sn = (sb + 5 < SEQ) ? sb + 5 : SEQ - 1;
          int tn = LDT(sn); F1 = __expf(LDF(sn)); G1 = LDE(sn, tn); t1 = tn; k1 = LDM(sn); }
        STEP(sb + 2, F2, t2, k2, G2);
        { int sn = (sb + 6 < SEQ) ? sb + 6 : SEQ - 1;
          int tn = LDT(sn); F2 = __expf(LDF(sn)); G2 = LDE(sn, tn); t2 = tn; k2 = LDM(sn); }
        STEP(sb + 3, F3, t3, k3, G3);
        { int sn = (sb + 7 < SEQ) ? sb + 7 : SEQ - 1;
          int tn = LDT(sn); F3 = __expf(LDF(sn)); G3 = LDE(sn, tn); t3 = tn; k3 = LDM(sn); }
    }

    // --- final forward score: log(sum_j u[j]*exp(trans[STOP,j])) + esum*ln2 ---
    float us = u * estop;
    #pragma unroll
    for (int off = 32; off >= 1; off >>= 1) us += __shfl_xor(us, off);
    float fwd = __logf(us) + (float)esum * 0.69314718f;

    // --- gold: stop transition from tags[length-1] ---
    int li   = (msumv > 0) ? (msumv - 1) : 0;
    int ltag = tags[li * BATCH + b];
    gold += tlds[TSTOP * NTAG + ltag];

    if (lane == 0) { part[b] = fwd - gold; msum[b] = msumv; }
    #undef LDF
    #undef LDT
    #undef LDM
    #undef LDE
}

// ---------------------------------------------------------------------------
// Kernel 2: deterministic reduction  out = sum(part) / sum(msum)
// ---------------------------------------------------------------------------
__global__ __launch_bounds__(256) void crf_reduce_kernel(
    const float* __restrict__ part, const int* __restrict__ msum,
    float* __restrict__ out)
{
    const int tid = threadIdx.x;
    float s = 0.f;
    int   m = 0;
    for (int k = tid; k < BATCH; k += 256) { s += part[k]; m += msum[k]; }
    #pragma unroll
    for (int off = 32; off >= 1; off >>= 1) {
        s += __shfl_xor(s, off);
        m += __shfl_xor(m, off);
    }
    __shared__ float sl[4];
    __shared__ int   ml[4];
    if ((tid & 63) == 0) { sl[tid >> 6] = s; ml[tid >> 6] = m; }
    __syncthreads();
    if (tid == 0)
        out[0] = (sl[0] + sl[1] + sl[2] + sl[3]) /
                 (float)(ml[0] + ml[1] + ml[2] + ml[3]);
}

extern "C" void kernel_launch(void* const* d_in, const int* in_sizes, int n_in,
                              void* d_out, int out_size, void* d_ws, size_t ws_size,
                              hipStream_t stream)
{
    const float* em   = (const float*)d_in[0];
    const float* tr   = (const float*)d_in[1];
    const int*   tags = (const int*)d_in[2];
    const int*   mask = (const int*)d_in[3];

    float* part = (float*)d_ws;
    int*   msum = (int*)((char*)d_ws + BATCH * sizeof(float));
    float* out  = (float*)d_out;

    crf_fwd_kernel<<<BATCH / NW, 64 * NW, 0, stream>>>(em, tr, tags, mask, part, msum);
    crf_reduce_kernel<<<1, 256, 0, stream>>>(part, msum, out);
}

// Round 3
// 305.464 us; speedup vs baseline: 1.0837x; 1.0837x over previous
//
#include <hip/hip_runtime.h>

#define SEQ    512
#define BATCH  1024
#define NTAG   54
#define TSTART 52
#define TSTOP  53
#define NW     4   // waves (batch elements) per block

// ---------------------------------------------------------------------------
// Linear-space CRF forward, readlane-broadcast matvec, gold path in a
// time-parallel prepass. wave = batch element, lane = tag j.
//
//   u[j] = exp(alpha[j] - esum*ln2)
//   step: u' = (sum_i Elin[j,i]*u[i]) * (exp(feat[j]) * 2^-e_lag)
//   Elin[j,i] = exp(trans[j,i])  (54 VGPRs/lane, constant)
//   e_lag = exponent of readlane(u,0) from previous step (SALU, off-chain)
//   broadcast of u via v_readlane -> SGPR, consumed straight by v_fmac.
// Main-loop memory: one 54-lane emission load + one uniform mask load per
// step, prefetched 8 deep. No DS ops, no dependent gathers.
// ---------------------------------------------------------------------------

#define MATVEC_STEP(FV, MK) do {                                              \
    float efs_ = (FV) * __uint_as_float((unsigned)(127 - e_lag) << 23);       \
    float a0_ = 0.f, a1_ = 0.f, a2_ = 0.f, a3_ = 0.f;                         \
    int uu_ = __float_as_int(u);                                              \
    _Pragma("unroll")                                                         \
    for (int i_ = 0; i_ < 52; i_ += 4) {                                      \
        float s0_ = __int_as_float(__builtin_amdgcn_readlane(uu_, i_ + 0));   \
        float s1_ = __int_as_float(__builtin_amdgcn_readlane(uu_, i_ + 1));   \
        float s2_ = __int_as_float(__builtin_amdgcn_readlane(uu_, i_ + 2));   \
        float s3_ = __int_as_float(__builtin_amdgcn_readlane(uu_, i_ + 3));   \
        a0_ = fmaf(Elin[i_ + 0], s0_, a0_);                                   \
        a1_ = fmaf(Elin[i_ + 1], s1_, a1_);                                   \
        a2_ = fmaf(Elin[i_ + 2], s2_, a2_);                                   \
        a3_ = fmaf(Elin[i_ + 3], s3_, a3_);                                   \
    }                                                                         \
    {                                                                         \
        float s0_ = __int_as_float(__builtin_amdgcn_readlane(uu_, 52));       \
        float s1_ = __int_as_float(__builtin_amdgcn_readlane(uu_, 53));       \
        a0_ = fmaf(Elin[52], s0_, a0_);                                       \
        a1_ = fmaf(Elin[53], s1_, a1_);                                       \
    }                                                                         \
    float w_  = (a0_ + a1_) + (a2_ + a3_);                                    \
    float un_ = w_ * efs_;                                                    \
    bool  up_ = (MK) > 0;                                                     \
    u = up_ ? un_ : u;                                                        \
    esum += up_ ? e_lag : 0;                                                  \
    unsigned ub_ = (unsigned)__builtin_amdgcn_readlane(__float_as_int(u), 0); \
    int en_ = (int)((ub_ >> 23) & 255u) - 127;                                \
    e_lag = en_ < -40 ? -40 : (en_ > 40 ? 40 : en_);                          \
} while (0)

__global__ __launch_bounds__(64 * NW) void crf_fwd_kernel(
    const float* __restrict__ em, const float* __restrict__ tr,
    const int* __restrict__ tags, const int* __restrict__ mask,
    float* __restrict__ part, int* __restrict__ msum)
{
    __shared__ float tlds[NTAG * NTAG];

    const int tid = threadIdx.x;
    for (int k = tid; k < NTAG * NTAG; k += 64 * NW) tlds[k] = tr[k];
    __syncthreads();

    const int wv   = tid >> 6;
    const int lane = tid & 63;
    const int b    = blockIdx.x * NW + wv;
    const size_t bT = (size_t)b * NTAG;

    // --- Elin = exp(trans) rows, register-resident ---
    float Elin[NTAG];
    #pragma unroll
    for (int i = 0; i < NTAG; ++i)
        Elin[i] = (lane < NTAG) ? __expf(tlds[lane * NTAG + i]) : 0.f;
    float estop = (lane < NTAG) ? __expf(tlds[TSTOP * NTAG + lane]) : 0.f;

    // =======================================================================
    // Gold prepass: time-parallel (lane l handles steps l, l+64, ..., l+448)
    // =======================================================================
    float goldp = 0.f;
    int   msump = 0;
    #pragma unroll
    for (int r = 0; r < 8; ++r) {
        int s  = r * 64 + lane;
        int tg = tags[s * BATCH + b];
        int mk = mask[s * BATCH + b];
        int tp = (s == 0) ? TSTART : tags[(s - 1) * BATCH + b];
        float emv = em[(size_t)s * (BATCH * NTAG) + bT + tg];
        float trv = tlds[tg * NTAG + tp];
        float mf  = (s == 0) ? 1.f : (float)mk;
        goldp = fmaf(trv + emv, mf, goldp);
        msump += mk;
    }
    #pragma unroll
    for (int off = 32; off >= 1; off >>= 1) {
        goldp += __shfl_xor(goldp, off);
        msump += __shfl_xor(msump, off);
    }

    // =======================================================================
    // Serial forward recursion
    // =======================================================================
    float u     = (lane == TSTART) ? 1.f : 0.f;
    int   esum  = 0;
    int   e_lag = 0;

    #define LDF(S) ((lane < NTAG) ? em[(size_t)(S) * (BATCH * NTAG) + bT + lane] : 0.f)
    #define LDM(S) (mask[(S) * BATCH + b])

    float F0 = __expf(LDF(0)), F1 = __expf(LDF(1)), F2 = __expf(LDF(2)), F3 = __expf(LDF(3));
    float F4 = __expf(LDF(4)), F5 = __expf(LDF(5)), F6 = __expf(LDF(6)), F7 = __expf(LDF(7));
    int   k0 = LDM(0), k1 = LDM(1), k2 = LDM(2), k3 = LDM(3);
    int   k4 = LDM(4), k5 = LDM(5), k6 = LDM(6), k7 = LDM(7);

    for (int sb = 0; sb < SEQ; sb += 8) {
        MATVEC_STEP(F0, k0);
        { int sn = (sb +  8 < SEQ) ? sb +  8 : SEQ - 1; F0 = __expf(LDF(sn)); k0 = LDM(sn); }
        MATVEC_STEP(F1, k1);
        { int sn = (sb +  9 < SEQ) ? sb +  9 : SEQ - 1; F1 = __expf(LDF(sn)); k1 = LDM(sn); }
        MATVEC_STEP(F2, k2);
        { int sn = (sb + 10 < SEQ) ? sb + 10 : SEQ - 1; F2 = __expf(LDF(sn)); k2 = LDM(sn); }
        MATVEC_STEP(F3, k3);
        { int sn = (sb + 11 < SEQ) ? sb + 11 : SEQ - 1; F3 = __expf(LDF(sn)); k3 = LDM(sn); }
        MATVEC_STEP(F4, k4);
        { int sn = (sb + 12 < SEQ) ? sb + 12 : SEQ - 1; F4 = __expf(LDF(sn)); k4 = LDM(sn); }
        MATVEC_STEP(F5, k5);
        { int sn = (sb + 13 < SEQ) ? sb + 13 : SEQ - 1; F5 = __expf(LDF(sn)); k5 = LDM(sn); }
        MATVEC_STEP(F6, k6);
        { int sn = (sb + 14 < SEQ) ? sb + 14 : SEQ - 1; F6 = __expf(LDF(sn)); k6 = LDM(sn); }
        MATVEC_STEP(F7, k7);
        { int sn = (sb + 15 < SEQ) ? sb + 15 : SEQ - 1; F7 = __expf(LDF(sn)); k7 = LDM(sn); }
    }

    // --- final forward score: log(sum_j u[j]*exp(trans[STOP,j])) + esum*ln2 ---
    float us = u * estop;
    #pragma unroll
    for (int off = 32; off >= 1; off >>= 1) us += __shfl_xor(us, off);
    float fwd = __logf(us) + (float)esum * 0.69314718f;

    // --- gold: stop transition from tags[length-1] ---
    int li   = (msump > 0) ? (msump - 1) : 0;
    int ltag = tags[li * BATCH + b];
    float gold = goldp + tlds[TSTOP * NTAG + ltag];

    if (lane == 0) { part[b] = fwd - gold; msum[b] = msump; }
    #undef LDF
    #undef LDM
}

// ---------------------------------------------------------------------------
// Kernel 2: deterministic reduction  out = sum(part) / sum(msum)
// ---------------------------------------------------------------------------
__global__ __launch_bounds__(256) void crf_reduce_kernel(
    const float* __restrict__ part, const int* __restrict__ msum,
    float* __restrict__ out)
{
    const int tid = threadIdx.x;
    float s = 0.f;
    int   m = 0;
    for (int k = tid; k < BATCH; k += 256) { s += part[k]; m += msum[k]; }
    #pragma unroll
    for (int off = 32; off >= 1; off >>= 1) {
        s += __shfl_xor(s, off);
        m += __shfl_xor(m, off);
    }
    __shared__ float sl[4];
    __shared__ int   ml[4];
    if ((tid & 63) == 0) { sl[tid >> 6] = s; ml[tid >> 6] = m; }
    __syncthreads();
    if (tid == 0)
        out[0] = (sl[0] + sl[1] + sl[2] + sl[3]) /
                 (float)(ml[0] + ml[1] + ml[2] + ml[3]);
}

extern "C" void kernel_launch(void* const* d_in, const int* in_sizes, int n_in,
                              void* d_out, int out_size, void* d_ws, size_t ws_size,
                              hipStream_t stream)
{
    const float* em   = (const float*)d_in[0];
    const float* tr   = (const float*)d_in[1];
    const int*   tags = (const int*)d_in[2];
    const int*   mask = (const int*)d_in[3];

    float* part = (float*)d_ws;
    int*   msumw = (int*)((char*)d_ws + BATCH * sizeof(float));
    float* out  = (float*)d_out;

    crf_fwd_kernel<<<BATCH / NW, 64 * NW, 0, stream>>>(em, tr, tags, mask, part, msumw);
    crf_reduce_kernel<<<1, 256, 0, stream>>>(part, msumw, out);
}

// Round 4
// 183.859 us; speedup vs baseline: 1.8004x; 1.6614x over previous
//
#include <hip/hip_runtime.h>

#define SEQ    512
#define BATCH  1024
#define NTAG   54
#define TSTART 52
#define TSTOP  53
#define NW     4   // waves (batch elements) per block

// ---------------------------------------------------------------------------
// Linear-space CRF forward, readlane-broadcast matvec, gold path in a
// time-parallel prepass. wave = batch element, lane = tag j.
//
//   u[j] = exp(alpha[j] - esum*ln2)
//   step: u' = (sum_i Elin[j,i]*u[i]) * (exp(feat[j]) * 2^-e_lag)
//   Elin[j,i] = exp(trans[j,i])  (54 VGPRs/lane, constant)
//   e_lag = exponent of readlane(u,0) from previous step (off-chain)
//
// KEY (round-4 fix): prefetch RAW emission floats 8 steps deep; __expf is
// applied at USE time, so no vmcnt(0) stall right after load issue. The
// exp depends on an 8-step-old load and feeds only the final multiply.
// ---------------------------------------------------------------------------

#define MATVEC_STEP(FV, MK) do {                                              \
    float efs_ = __expf(FV) * __uint_as_float((unsigned)(127 - e_lag) << 23); \
    float a0_ = 0.f, a1_ = 0.f, a2_ = 0.f, a3_ = 0.f;                         \
    int uu_ = __float_as_int(u);                                              \
    _Pragma("unroll")                                                         \
    for (int i_ = 0; i_ < 52; i_ += 4) {                                      \
        float s0_ = __int_as_float(__builtin_amdgcn_readlane(uu_, i_ + 0));   \
        float s1_ = __int_as_float(__builtin_amdgcn_readlane(uu_, i_ + 1));   \
        float s2_ = __int_as_float(__builtin_amdgcn_readlane(uu_, i_ + 2));   \
        float s3_ = __int_as_float(__builtin_amdgcn_readlane(uu_, i_ + 3));   \
        a0_ = fmaf(Elin[i_ + 0], s0_, a0_);                                   \
        a1_ = fmaf(Elin[i_ + 1], s1_, a1_);                                   \
        a2_ = fmaf(Elin[i_ + 2], s2_, a2_);                                   \
        a3_ = fmaf(Elin[i_ + 3], s3_, a3_);                                   \
    }                                                                         \
    {                                                                         \
        float s0_ = __int_as_float(__builtin_amdgcn_readlane(uu_, 52));       \
        float s1_ = __int_as_float(__builtin_amdgcn_readlane(uu_, 53));       \
        a0_ = fmaf(Elin[52], s0_, a0_);                                       \
        a1_ = fmaf(Elin[53], s1_, a1_);                                       \
    }                                                                         \
    float w_  = (a0_ + a1_) + (a2_ + a3_);                                    \
    float un_ = w_ * efs_;                                                    \
    bool  up_ = (MK) > 0;                                                     \
    u = up_ ? un_ : u;                                                        \
    esum += up_ ? e_lag : 0;                                                  \
    unsigned ub_ = (unsigned)__builtin_amdgcn_readlane(__float_as_int(u), 0); \
    int en_ = (int)((ub_ >> 23) & 255u) - 127;                                \
    e_lag = en_ < -40 ? -40 : (en_ > 40 ? 40 : en_);                          \
} while (0)

__global__ __launch_bounds__(64 * NW) void crf_fwd_kernel(
    const float* __restrict__ em, const float* __restrict__ tr,
    const int* __restrict__ tags, const int* __restrict__ mask,
    float* __restrict__ part, int* __restrict__ msum)
{
    __shared__ float tlds[NTAG * NTAG];

    const int tid = threadIdx.x;
    for (int k = tid; k < NTAG * NTAG; k += 64 * NW) tlds[k] = tr[k];
    __syncthreads();

    const int wv   = tid >> 6;
    const int lane = tid & 63;
    const int b    = blockIdx.x * NW + wv;
    const size_t bT = (size_t)b * NTAG;

    // --- Elin = exp(trans) rows, register-resident ---
    float Elin[NTAG];
    #pragma unroll
    for (int i = 0; i < NTAG; ++i)
        Elin[i] = (lane < NTAG) ? __expf(tlds[lane * NTAG + i]) : 0.f;
    float estop = (lane < NTAG) ? __expf(tlds[TSTOP * NTAG + lane]) : 0.f;

    // =======================================================================
    // Gold prepass: time-parallel (lane l handles steps l, l+64, ..., l+448)
    // =======================================================================
    float goldp = 0.f;
    int   msump = 0;
    #pragma unroll
    for (int r = 0; r < 8; ++r) {
        int s  = r * 64 + lane;
        int tg = tags[s * BATCH + b];
        int mk = mask[s * BATCH + b];
        int tp = (s == 0) ? TSTART : tags[(s - 1) * BATCH + b];
        float emv = em[(size_t)s * (BATCH * NTAG) + bT + tg];
        float trv = tlds[tg * NTAG + tp];
        float mf  = (s == 0) ? 1.f : (float)mk;
        goldp = fmaf(trv + emv, mf, goldp);
        msump += mk;
    }
    #pragma unroll
    for (int off = 32; off >= 1; off >>= 1) {
        goldp += __shfl_xor(goldp, off);
        msump += __shfl_xor(msump, off);
    }

    // =======================================================================
    // Serial forward recursion (raw prefetch, exp-at-use)
    // =======================================================================
    float u     = (lane == TSTART) ? 1.f : 0.f;
    int   esum  = 0;
    int   e_lag = 0;

    #define LDF(S) ((lane < NTAG) ? em[(size_t)(S) * (BATCH * NTAG) + bT + lane] : 0.f)
    #define LDM(S) (mask[(S) * BATCH + b])

    float F0 = LDF(0), F1 = LDF(1), F2 = LDF(2), F3 = LDF(3);
    float F4 = LDF(4), F5 = LDF(5), F6 = LDF(6), F7 = LDF(7);
    int   k0 = LDM(0), k1 = LDM(1), k2 = LDM(2), k3 = LDM(3);
    int   k4 = LDM(4), k5 = LDM(5), k6 = LDM(6), k7 = LDM(7);

    for (int sb = 0; sb < SEQ; sb += 8) {
        MATVEC_STEP(F0, k0);
        { int sn = (sb +  8 < SEQ) ? sb +  8 : SEQ - 1; F0 = LDF(sn); k0 = LDM(sn); }
        MATVEC_STEP(F1, k1);
        { int sn = (sb +  9 < SEQ) ? sb +  9 : SEQ - 1; F1 = LDF(sn); k1 = LDM(sn); }
        MATVEC_STEP(F2, k2);
        { int sn = (sb + 10 < SEQ) ? sb + 10 : SEQ - 1; F2 = LDF(sn); k2 = LDM(sn); }
        MATVEC_STEP(F3, k3);
        { int sn = (sb + 11 < SEQ) ? sb + 11 : SEQ - 1; F3 = LDF(sn); k3 = LDM(sn); }
        MATVEC_STEP(F4, k4);
        { int sn = (sb + 12 < SEQ) ? sb + 12 : SEQ - 1; F4 = LDF(sn); k4 = LDM(sn); }
        MATVEC_STEP(F5, k5);
        { int sn = (sb + 13 < SEQ) ? sb + 13 : SEQ - 1; F5 = LDF(sn); k5 = LDM(sn); }
        MATVEC_STEP(F6, k6);
        { int sn = (sb + 14 < SEQ) ? sb + 14 : SEQ - 1; F6 = LDF(sn); k6 = LDM(sn); }
        MATVEC_STEP(F7, k7);
        { int sn = (sb + 15 < SEQ) ? sb + 15 : SEQ - 1; F7 = LDF(sn); k7 = LDM(sn); }
    }

    // --- final forward score: log(sum_j u[j]*exp(trans[STOP,j])) + esum*ln2 ---
    float us = u * estop;
    #pragma unroll
    for (int off = 32; off >= 1; off >>= 1) us += __shfl_xor(us, off);
    float fwd = __logf(us) + (float)esum * 0.69314718f;

    // --- gold: stop transition from tags[length-1] ---
    int li   = (msump > 0) ? (msump - 1) : 0;
    int ltag = tags[li * BATCH + b];
    float gold = goldp + tlds[TSTOP * NTAG + ltag];

    if (lane == 0) { part[b] = fwd - gold; msum[b] = msump; }
    #undef LDF
    #undef LDM
}

// ---------------------------------------------------------------------------
// Kernel 2: deterministic reduction  out = sum(part) / sum(msum)
// ---------------------------------------------------------------------------
__global__ __launch_bounds__(256) void crf_reduce_kernel(
    const float* __restrict__ part, const int* __restrict__ msum,
    float* __restrict__ out)
{
    const int tid = threadIdx.x;
    float s = 0.f;
    int   m = 0;
    for (int k = tid; k < BATCH; k += 256) { s += part[k]; m += msum[k]; }
    #pragma unroll
    for (int off = 32; off >= 1; off >>= 1) {
        s += __shfl_xor(s, off);
        m += __shfl_xor(m, off);
    }
    __shared__ float sl[4];
    __shared__ int   ml[4];
    if ((tid & 63) == 0) { sl[tid >> 6] = s; ml[tid >> 6] = m; }
    __syncthreads();
    if (tid == 0)
        out[0] = (sl[0] + sl[1] + sl[2] + sl[3]) /
                 (float)(ml[0] + ml[1] + ml[2] + ml[3]);
}

extern "C" void kernel_launch(void* const* d_in, const int* in_sizes, int n_in,
                              void* d_out, int out_size, void* d_ws, size_t ws_size,
                              hipStream_t stream)
{
    const float* em   = (const float*)d_in[0];
    const float* tr   = (const float*)d_in[1];
    const int*   tags = (const int*)d_in[2];
    const int*   mask = (const int*)d_in[3];

    float* part  = (float*)d_ws;
    int*   msumw = (int*)((char*)d_ws + BATCH * sizeof(float));
    float* out   = (float*)d_out;

    crf_fwd_kernel<<<BATCH / NW, 64 * NW, 0, stream>>>(em, tr, tags, mask, part, msumw);
    crf_reduce_kernel<<<1, 256, 0, stream>>>(part, msumw, out);
}

// Round 5
// 183.582 us; speedup vs baseline: 1.8031x; 1.0015x over previous
//
#include <hip/hip_runtime.h>

#define SEQ    512
#define BATCH  1024
#define NTAG   54
#define TSTART 52
#define TSTOP  53
#define NW     4   // waves (batch elements) per block

// ---------------------------------------------------------------------------
// Linear-space CRF forward, readlane-broadcast matvec, gold path in a
// time-parallel prepass. wave = batch element, lane = tag j.
//
//   u[j] = exp(alpha[j] - esum*ln2)
//   step: u' = (sum_i Elin[j,i]*u[i]) * (exp(feat[j]) * 2^-e_lag)
//   Elin[j,i] = exp(trans[j,i])  (54 VGPRs/lane, constant)
//   e_lag = exponent of readlane(u,0) from previous step (off-chain)
//
// Round-5 fix: __launch_bounds__(256, 1). Grid is structurally 1 wave/SIMD
// (1024 waves on 1024 SIMDs), so occupancy is free — let the allocator use
// the full unified VGPR file so Elin[54] + 8-deep prefetch stay resident
// (round 4 spilled: VGPR_Count=56 < ~90 live values).
// ---------------------------------------------------------------------------

#define MATVEC_STEP(FV, MK) do {                                              \
    float efs_ = __expf(FV) * __uint_as_float((unsigned)(127 - e_lag) << 23); \
    float a0_ = 0.f, a1_ = 0.f, a2_ = 0.f, a3_ = 0.f;                         \
    int uu_ = __float_as_int(u);                                              \
    _Pragma("unroll")                                                         \
    for (int i_ = 0; i_ < 52; i_ += 4) {                                      \
        float s0_ = __int_as_float(__builtin_amdgcn_readlane(uu_, i_ + 0));   \
        float s1_ = __int_as_float(__builtin_amdgcn_readlane(uu_, i_ + 1));   \
        float s2_ = __int_as_float(__builtin_amdgcn_readlane(uu_, i_ + 2));   \
        float s3_ = __int_as_float(__builtin_amdgcn_readlane(uu_, i_ + 3));   \
        a0_ = fmaf(Elin[i_ + 0], s0_, a0_);                                   \
        a1_ = fmaf(Elin[i_ + 1], s1_, a1_);                                   \
        a2_ = fmaf(Elin[i_ + 2], s2_, a2_);                                   \
        a3_ = fmaf(Elin[i_ + 3], s3_, a3_);                                   \
    }                                                                         \
    {                                                                         \
        float s0_ = __int_as_float(__builtin_amdgcn_readlane(uu_, 52));       \
        float s1_ = __int_as_float(__builtin_amdgcn_readlane(uu_, 53));       \
        a0_ = fmaf(Elin[52], s0_, a0_);                                       \
        a1_ = fmaf(Elin[53], s1_, a1_);                                       \
    }                                                                         \
    float w_  = (a0_ + a1_) + (a2_ + a3_);                                    \
    float un_ = w_ * efs_;                                                    \
    bool  up_ = (MK) > 0;                                                     \
    u = up_ ? un_ : u;                                                        \
    esum += up_ ? e_lag : 0;                                                  \
    unsigned ub_ = (unsigned)__builtin_amdgcn_readlane(__float_as_int(u), 0); \
    int en_ = (int)((ub_ >> 23) & 255u) - 127;                                \
    e_lag = en_ < -40 ? -40 : (en_ > 40 ? 40 : en_);                          \
} while (0)

__global__ __launch_bounds__(64 * NW, 1) void crf_fwd_kernel(
    const float* __restrict__ em, const float* __restrict__ tr,
    const int* __restrict__ tags, const int* __restrict__ mask,
    float* __restrict__ part, int* __restrict__ msum)
{
    __shared__ float tlds[NTAG * NTAG];

    const int tid = threadIdx.x;
    for (int k = tid; k < NTAG * NTAG; k += 64 * NW) tlds[k] = tr[k];
    __syncthreads();

    const int wv   = tid >> 6;
    const int lane = tid & 63;
    const int b    = blockIdx.x * NW + wv;
    const size_t bT = (size_t)b * NTAG;

    // --- Elin = exp(trans) rows, register-resident ---
    float Elin[NTAG];
    #pragma unroll
    for (int i = 0; i < NTAG; ++i)
        Elin[i] = (lane < NTAG) ? __expf(tlds[lane * NTAG + i]) : 0.f;
    float estop = (lane < NTAG) ? __expf(tlds[TSTOP * NTAG + lane]) : 0.f;

    // =======================================================================
    // Gold prepass: time-parallel (lane l handles steps l, l+64, ..., l+448)
    // =======================================================================
    float goldp = 0.f;
    int   msump = 0;
    #pragma unroll
    for (int r = 0; r < 8; ++r) {
        int s  = r * 64 + lane;
        int tg = tags[s * BATCH + b];
        int mk = mask[s * BATCH + b];
        int tp = (s == 0) ? TSTART : tags[(s - 1) * BATCH + b];
        float emv = em[(size_t)s * (BATCH * NTAG) + bT + tg];
        float trv = tlds[tg * NTAG + tp];
        float mf  = (s == 0) ? 1.f : (float)mk;
        goldp = fmaf(trv + emv, mf, goldp);
        msump += mk;
    }
    #pragma unroll
    for (int off = 32; off >= 1; off >>= 1) {
        goldp += __shfl_xor(goldp, off);
        msump += __shfl_xor(msump, off);
    }

    // =======================================================================
    // Serial forward recursion (raw prefetch, exp-at-use)
    // =======================================================================
    float u     = (lane == TSTART) ? 1.f : 0.f;
    int   esum  = 0;
    int   e_lag = 0;

    #define LDF(S) ((lane < NTAG) ? em[(size_t)(S) * (BATCH * NTAG) + bT + lane] : 0.f)
    #define LDM(S) (mask[(S) * BATCH + b])

    float F0 = LDF(0), F1 = LDF(1), F2 = LDF(2), F3 = LDF(3);
    float F4 = LDF(4), F5 = LDF(5), F6 = LDF(6), F7 = LDF(7);
    int   k0 = LDM(0), k1 = LDM(1), k2 = LDM(2), k3 = LDM(3);
    int   k4 = LDM(4), k5 = LDM(5), k6 = LDM(6), k7 = LDM(7);

    for (int sb = 0; sb < SEQ; sb += 8) {
        MATVEC_STEP(F0, k0);
        { int sn = (sb +  8 < SEQ) ? sb +  8 : SEQ - 1; F0 = LDF(sn); k0 = LDM(sn); }
        MATVEC_STEP(F1, k1);
        { int sn = (sb +  9 < SEQ) ? sb +  9 : SEQ - 1; F1 = LDF(sn); k1 = LDM(sn); }
        MATVEC_STEP(F2, k2);
        { int sn = (sb + 10 < SEQ) ? sb + 10 : SEQ - 1; F2 = LDF(sn); k2 = LDM(sn); }
        MATVEC_STEP(F3, k3);
        { int sn = (sb + 11 < SEQ) ? sb + 11 : SEQ - 1; F3 = LDF(sn); k3 = LDM(sn); }
        MATVEC_STEP(F4, k4);
        { int sn = (sb + 12 < SEQ) ? sb + 12 : SEQ - 1; F4 = LDF(sn); k4 = LDM(sn); }
        MATVEC_STEP(F5, k5);
        { int sn = (sb + 13 < SEQ) ? sb + 13 : SEQ - 1; F5 = LDF(sn); k5 = LDM(sn); }
        MATVEC_STEP(F6, k6);
        { int sn = (sb + 14 < SEQ) ? sb + 14 : SEQ - 1; F6 = LDF(sn); k6 = LDM(sn); }
        MATVEC_STEP(F7, k7);
        { int sn = (sb + 15 < SEQ) ? sb + 15 : SEQ - 1; F7 = LDF(sn); k7 = LDM(sn); }
    }

    // --- final forward score: log(sum_j u[j]*exp(trans[STOP,j])) + esum*ln2 ---
    float us = u * estop;
    #pragma unroll
    for (int off = 32; off >= 1; off >>= 1) us += __shfl_xor(us, off);
    float fwd = __logf(us) + (float)esum * 0.69314718f;

    // --- gold: stop transition from tags[length-1] ---
    int li   = (msump > 0) ? (msump - 1) : 0;
    int ltag = tags[li * BATCH + b];
    float gold = goldp + tlds[TSTOP * NTAG + ltag];

    if (lane == 0) { part[b] = fwd - gold; msum[b] = msump; }
    #undef LDF
    #undef LDM
}

// ---------------------------------------------------------------------------
// Kernel 2: deterministic reduction  out = sum(part) / sum(msum)
// ---------------------------------------------------------------------------
__global__ __launch_bounds__(256) void crf_reduce_kernel(
    const float* __restrict__ part, const int* __restrict__ msum,
    float* __restrict__ out)
{
    const int tid = threadIdx.x;
    float s = 0.f;
    int   m = 0;
    for (int k = tid; k < BATCH; k += 256) { s += part[k]; m += msum[k]; }
    #pragma unroll
    for (int off = 32; off >= 1; off >>= 1) {
        s += __shfl_xor(s, off);
        m += __shfl_xor(m, off);
    }
    __shared__ float sl[4];
    __shared__ int   ml[4];
    if ((tid & 63) == 0) { sl[tid >> 6] = s; ml[tid >> 6] = m; }
    __syncthreads();
    if (tid == 0)
        out[0] = (sl[0] + sl[1] + sl[2] + sl[3]) /
                 (float)(ml[0] + ml[1] + ml[2] + ml[3]);
}

extern "C" void kernel_launch(void* const* d_in, const int* in_sizes, int n_in,
                              void* d_out, int out_size, void* d_ws, size_t ws_size,
                              hipStream_t stream)
{
    const float* em   = (const float*)d_in[0];
    const float* tr   = (const float*)d_in[1];
    const int*   tags = (const int*)d_in[2];
    const int*   mask = (const int*)d_in[3];

    float* part  = (float*)d_ws;
    int*   msumw = (int*)((char*)d_ws + BATCH * sizeof(float));
    float* out   = (float*)d_out;

    crf_fwd_kernel<<<BATCH / NW, 64 * NW, 0, stream>>>(em, tr, tags, mask, part, msumw);
    crf_reduce_kernel<<<1, 256, 0, stream>>>(part, msumw, out);
}

// Round 6
// 183.453 us; speedup vs baseline: 1.8044x; 1.0007x over previous
//
#include <hip/hip_runtime.h>

#define SEQ    512
#define BATCH  1024
#define NTAG   54
#define TSTART 52
#define TSTOP  53
#define NW     4   // waves (batch elements) per block

// ---------------------------------------------------------------------------
// Linear-space CRF forward, readlane-broadcast matvec, gold path in a
// time-parallel prepass. wave = batch element, lane = tag j.
//
//   u[j] = exp(alpha[j] - esum*ln2)
//   step: u' = (sum_i Elin[j,i]*u[i]) * (exp(feat[j]) * 2^-e_lag)
//   Elin[j,i] = exp(trans[j,i])  (54 VGPRs/lane, constant)
//   e_lag = exponent of readlane(u,0) from previous step (off-chain)
//
// Round-6 fix: pin Elin[i] into VGPRs with opaque volatile asm. Rounds 4/5
// showed VGPR_Count=56: MachineLICM kept rematerializing ds_read+v_exp for
// Elin inside the loop (~138 extra VALU instr/step). The "+v" asm makes each
// Elin[i] un-rematerializable and un-sinkable, forcing residency (budget is
// 512 VGPRs via __launch_bounds__(256,1); grid is 1 wave/SIMD so occupancy
// costs nothing).
// ---------------------------------------------------------------------------

#define MATVEC_STEP(FV, MK) do {                                              \
    float efs_ = __expf(FV) * __uint_as_float((unsigned)(127 - e_lag) << 23); \
    float a0_ = 0.f, a1_ = 0.f, a2_ = 0.f, a3_ = 0.f;                         \
    int uu_ = __float_as_int(u);                                              \
    _Pragma("unroll")                                                         \
    for (int i_ = 0; i_ < 52; i_ += 4) {                                      \
        float s0_ = __int_as_float(__builtin_amdgcn_readlane(uu_, i_ + 0));   \
        float s1_ = __int_as_float(__builtin_amdgcn_readlane(uu_, i_ + 1));   \
        float s2_ = __int_as_float(__builtin_amdgcn_readlane(uu_, i_ + 2));   \
        float s3_ = __int_as_float(__builtin_amdgcn_readlane(uu_, i_ + 3));   \
        a0_ = fmaf(Elin[i_ + 0], s0_, a0_);                                   \
        a1_ = fmaf(Elin[i_ + 1], s1_, a1_);                                   \
        a2_ = fmaf(Elin[i_ + 2], s2_, a2_);                                   \
        a3_ = fmaf(Elin[i_ + 3], s3_, a3_);                                   \
    }                                                                         \
    {                                                                         \
        float s0_ = __int_as_float(__builtin_amdgcn_readlane(uu_, 52));       \
        float s1_ = __int_as_float(__builtin_amdgcn_readlane(uu_, 53));       \
        a0_ = fmaf(Elin[52], s0_, a0_);                                       \
        a1_ = fmaf(Elin[53], s1_, a1_);                                       \
    }                                                                         \
    float w_  = (a0_ + a1_) + (a2_ + a3_);                                    \
    float un_ = w_ * efs_;                                                    \
    bool  up_ = (MK) > 0;                                                     \
    u = up_ ? un_ : u;                                                        \
    esum += up_ ? e_lag : 0;                                                  \
    unsigned ub_ = (unsigned)__builtin_amdgcn_readlane(__float_as_int(u), 0); \
    int en_ = (int)((ub_ >> 23) & 255u) - 127;                                \
    e_lag = en_ < -40 ? -40 : (en_ > 40 ? 40 : en_);                          \
} while (0)

__global__ __launch_bounds__(64 * NW, 1) void crf_fwd_kernel(
    const float* __restrict__ em, const float* __restrict__ tr,
    const int* __restrict__ tags, const int* __restrict__ mask,
    float* __restrict__ part, int* __restrict__ msum)
{
    __shared__ float tlds[NTAG * NTAG];

    const int tid = threadIdx.x;
    for (int k = tid; k < NTAG * NTAG; k += 64 * NW) tlds[k] = tr[k];
    __syncthreads();

    const int wv   = tid >> 6;
    const int lane = tid & 63;
    const int b    = blockIdx.x * NW + wv;
    const size_t bT = (size_t)b * NTAG;

    // --- Elin = exp(trans) rows, pinned register-resident ---
    float Elin[NTAG];
    #pragma unroll
    for (int i = 0; i < NTAG; ++i) {
        Elin[i] = (lane < NTAG) ? __expf(tlds[lane * NTAG + i]) : 0.f;
        asm volatile("" : "+v"(Elin[i]));   // pin: no remat, no sink into loop
    }
    float estop = (lane < NTAG) ? __expf(tlds[TSTOP * NTAG + lane]) : 0.f;

    // =======================================================================
    // Gold prepass: time-parallel (lane l handles steps l, l+64, ..., l+448)
    // =======================================================================
    float goldp = 0.f;
    int   msump = 0;
    #pragma unroll
    for (int r = 0; r < 8; ++r) {
        int s  = r * 64 + lane;
        int tg = tags[s * BATCH + b];
        int mk = mask[s * BATCH + b];
        int tp = (s == 0) ? TSTART : tags[(s - 1) * BATCH + b];
        float emv = em[(size_t)s * (BATCH * NTAG) + bT + tg];
        float trv = tlds[tg * NTAG + tp];
        float mf  = (s == 0) ? 1.f : (float)mk;
        goldp = fmaf(trv + emv, mf, goldp);
        msump += mk;
    }
    #pragma unroll
    for (int off = 32; off >= 1; off >>= 1) {
        goldp += __shfl_xor(goldp, off);
        msump += __shfl_xor(msump, off);
    }

    // =======================================================================
    // Serial forward recursion (raw prefetch, exp-at-use)
    // =======================================================================
    float u     = (lane == TSTART) ? 1.f : 0.f;
    int   esum  = 0;
    int   e_lag = 0;

    #define LDF(S) ((lane < NTAG) ? em[(size_t)(S) * (BATCH * NTAG) + bT + lane] : 0.f)
    #define LDM(S) (mask[(S) * BATCH + b])

    float F0 = LDF(0), F1 = LDF(1), F2 = LDF(2), F3 = LDF(3);
    float F4 = LDF(4), F5 = LDF(5), F6 = LDF(6), F7 = LDF(7);
    int   k0 = LDM(0), k1 = LDM(1), k2 = LDM(2), k3 = LDM(3);
    int   k4 = LDM(4), k5 = LDM(5), k6 = LDM(6), k7 = LDM(7);

    for (int sb = 0; sb < SEQ; sb += 8) {
        MATVEC_STEP(F0, k0);
        { int sn = (sb +  8 < SEQ) ? sb +  8 : SEQ - 1; F0 = LDF(sn); k0 = LDM(sn); }
        MATVEC_STEP(F1, k1);
        { int sn = (sb +  9 < SEQ) ? sb +  9 : SEQ - 1; F1 = LDF(sn); k1 = LDM(sn); }
        MATVEC_STEP(F2, k2);
        { int sn = (sb + 10 < SEQ) ? sb + 10 : SEQ - 1; F2 = LDF(sn); k2 = LDM(sn); }
        MATVEC_STEP(F3, k3);
        { int sn = (sb + 11 < SEQ) ? sb + 11 : SEQ - 1; F3 = LDF(sn); k3 = LDM(sn); }
        MATVEC_STEP(F4, k4);
        { int sn = (sb + 12 < SEQ) ? sb + 12 : SEQ - 1; F4 = LDF(sn); k4 = LDM(sn); }
        MATVEC_STEP(F5, k5);
        { int sn = (sb + 13 < SEQ) ? sb + 13 : SEQ - 1; F5 = LDF(sn); k5 = LDM(sn); }
        MATVEC_STEP(F6, k6);
        { int sn = (sb + 14 < SEQ) ? sb + 14 : SEQ - 1; F6 = LDF(sn); k6 = LDM(sn); }
        MATVEC_STEP(F7, k7);
        { int sn = (sb + 15 < SEQ) ? sb + 15 : SEQ - 1; F7 = LDF(sn); k7 = LDM(sn); }
    }

    // --- final forward score: log(sum_j u[j]*exp(trans[STOP,j])) + esum*ln2 ---
    float us = u * estop;
    #pragma unroll
    for (int off = 32; off >= 1; off >>= 1) us += __shfl_xor(us, off);
    float fwd = __logf(us) + (float)esum * 0.69314718f;

    // --- gold: stop transition from tags[length-1] ---
    int li   = (msump > 0) ? (msump - 1) : 0;
    int ltag = tags[li * BATCH + b];
    float gold = goldp + tlds[TSTOP * NTAG + ltag];

    if (lane == 0) { part[b] = fwd - gold; msum[b] = msump; }
    #undef LDF
    #undef LDM
}

// ---------------------------------------------------------------------------
// Kernel 2: deterministic reduction  out = sum(part) / sum(msum)
// ---------------------------------------------------------------------------
__global__ __launch_bounds__(256) void crf_reduce_kernel(
    const float* __restrict__ part, const int* __restrict__ msum,
    float* __restrict__ out)
{
    const int tid = threadIdx.x;
    float s = 0.f;
    int   m = 0;
    for (int k = tid; k < BATCH; k += 256) { s += part[k]; m += msum[k]; }
    #pragma unroll
    for (int off = 32; off >= 1; off >>= 1) {
        s += __shfl_xor(s, off);
        m += __shfl_xor(m, off);
    }
    __shared__ float sl[4];
    __shared__ int   ml[4];
    if ((tid & 63) == 0) { sl[tid >> 6] = s; ml[tid >> 6] = m; }
    __syncthreads();
    if (tid == 0)
        out[0] = (sl[0] + sl[1] + sl[2] + sl[3]) /
                 (float)(ml[0] + ml[1] + ml[2] + ml[3]);
}

extern "C" void kernel_launch(void* const* d_in, const int* in_sizes, int n_in,
                              void* d_out, int out_size, void* d_ws, size_t ws_size,
                              hipStream_t stream)
{
    const float* em   = (const float*)d_in[0];
    const float* tr   = (const float*)d_in[1];
    const int*   tags = (const int*)d_in[2];
    const int*   mask = (const int*)d_in[3];

    float* part  = (float*)d_ws;
    int*   msumw = (int*)((char*)d_ws + BATCH * sizeof(float));
    float* out   = (float*)d_out;

    crf_fwd_kernel<<<BATCH / NW, 64 * NW, 0, stream>>>(em, tr, tags, mask, part, msumw);
    crf_reduce_kernel<<<1, 256, 0, stream>>>(part, msumw, out);
}